// Round 19
// baseline (633.309 us; speedup 1.0000x reference)
//
#include <hip/hip_runtime.h>

typedef float  f32x4  __attribute__((ext_vector_type(4)));
typedef short  s16x8  __attribute__((ext_vector_type(8)));
typedef short  s16x4  __attribute__((ext_vector_type(4)));

__device__ __forceinline__ unsigned short f2bf(float f) {
    unsigned int u = __float_as_uint(f);
    return (unsigned short)((u + 0x7FFFu + ((u >> 16) & 1u)) >> 16);
}

__device__ __forceinline__ s16x8 cvt8(f32x4 a, f32x4 b) {
    union { unsigned int u[4]; s16x8 v; } r;
    asm("v_cvt_pk_bf16_f32 %0, %1, %2" : "=v"(r.u[0]) : "v"(a[0]), "v"(a[1]));
    asm("v_cvt_pk_bf16_f32 %0, %1, %2" : "=v"(r.u[1]) : "v"(a[2]), "v"(a[3]));
    asm("v_cvt_pk_bf16_f32 %0, %1, %2" : "=v"(r.u[2]) : "v"(b[0]), "v"(b[1]));
    asm("v_cvt_pk_bf16_f32 %0, %1, %2" : "=v"(r.u[3]) : "v"(b[2]), "v"(b[3]));
    return r.v;
}

__device__ __forceinline__ void lds_barrier() {
    asm volatile("s_waitcnt lgkmcnt(0)" ::: "memory");
    __builtin_amdgcn_s_barrier();
    asm volatile("" ::: "memory");
}

// ---------------------------------------------------------------------------
// Kernel 0: wt3 = FRAGMENT-MAJOR bf16 weights (verified R9/R11).
// ---------------------------------------------------------------------------
__global__ void prep_wt(const float* __restrict__ Wq,
                        const float* __restrict__ Wk,
                        const float* __restrict__ Wv,
                        unsigned char* __restrict__ wt3) {
    int n = blockIdx.x;                       // 0..383
    const float* W = (n < 128) ? Wq : ((n < 256) ? Wk : Wv);
    int h = n & 127;
    int n16 = n >> 4, lmn = n & 15;
    for (int k = threadIdx.x; k < 1024; k += blockDim.x) {
        unsigned short v = f2bf(W[(size_t)k * 128 + h]);
        int ks = k >> 6, rem = k & 63;
        int kkk = rem >> 5, l4_ = (rem >> 3) & 3, j = rem & 7;
        int lane = l4_ * 16 + lmn;
        size_t off = (size_t)(n16 * 32 + ks * 2 + kkk) * 1024 + lane * 16 + j * 2;
        *(unsigned short*)(wt3 + off) = v;
    }
}

// ---------------------------------------------------------------------------
// Kernel 1: QKV GEMM — R11 verbatim (best measured: qkv ~67us, total 76.8).
// ---------------------------------------------------------------------------
__global__ __launch_bounds__(512, 2) void qkv_gemm(
    const float* __restrict__ x,
    const unsigned char* __restrict__ wt3,
    unsigned short* __restrict__ qo,
    unsigned short* __restrict__ ko,
    unsigned short* __restrict__ vto) {

    __shared__ char smem[32768];              // A: 2 x [128][128B] swizzled

    const int tid = threadIdx.x;
    const int bm  = blockIdx.x;               // 0..255
    const int lane = tid & 63, wid = tid >> 6;
    const int lm = lane & 15, l4 = lane >> 4;

    f32x4 acc[8][3];
#pragma unroll
    for (int i = 0; i < 8; ++i)
#pragma unroll
        for (int j = 0; j < 3; ++j) acc[i][j] = (f32x4)0.f;

    const int ar  = tid >> 2;
    const int acb = (tid & 3) * 16;
    const float* xp = x + (size_t)(bm * 128 + ar) * 1024 + acb;
    const int aswz = (ar & 7) << 4;
    const int aw0 = ar * 128 + ((acb * 2) ^ aswz);
    const int aw1 = ar * 128 + ((acb * 2 + 16) ^ aswz);

    const unsigned char* wb = wt3 + (size_t)lane * 16;
    const unsigned char* wbq[3];
#pragma unroll
    for (int ni = 0; ni < 3; ++ni) wbq[ni] = wb + (size_t)(wid * 3 + ni) * 32768;

    int arow[8];
#pragma unroll
    for (int mi = 0; mi < 8; ++mi) arow[mi] = mi * 16 + lm;

    s16x8 af[8];
    s16x8 bqE0[3], bqE1[3], bqO0[3], bqO1[3];
    f32x4 pa0, pa1, pa2, pa3;

#define AFREAD(AB, KOFF)                                                       \
    do {                                                                       \
        _Pragma("unroll")                                                      \
        for (int mi = 0; mi < 8; ++mi)                                         \
            af[mi] = *(const s16x8*)(smem + (AB) + arow[mi] * 128 +            \
                      (((KOFF) + l4 * 16) ^ ((arow[mi] & 7) << 4)));           \
    } while (0)

#define MFMA3(BQ)                                                              \
    do {                                                                       \
        __builtin_amdgcn_s_setprio(1);                                         \
        _Pragma("unroll")                                                      \
        for (int ni = 0; ni < 3; ++ni)                                         \
            _Pragma("unroll")                                                  \
            for (int mi = 0; mi < 8; ++mi)                                     \
                acc[mi][ni] = __builtin_amdgcn_mfma_f32_16x16x32_bf16(         \
                    af[mi], (BQ)[ni], acc[mi][ni], 0, 0, 0);                   \
        __builtin_amdgcn_s_setprio(0);                                         \
    } while (0)

    {
        f32x4 a0 = *(const f32x4*)(xp);
        f32x4 a1 = *(const f32x4*)(xp + 4);
        f32x4 a2 = *(const f32x4*)(xp + 8);
        f32x4 a3 = *(const f32x4*)(xp + 12);
#pragma unroll
        for (int ni = 0; ni < 3; ++ni) {
            bqE0[ni] = *(const s16x8*)(wbq[ni]);
            bqE1[ni] = *(const s16x8*)(wbq[ni] + 1024);
        }
        *(s16x8*)(smem + aw0) = cvt8(a0, a1);
        *(s16x8*)(smem + aw1) = cvt8(a2, a3);
        pa0 = *(const f32x4*)(xp + 64);
        pa1 = *(const f32x4*)(xp + 68);
        pa2 = *(const f32x4*)(xp + 72);
        pa3 = *(const f32x4*)(xp + 76);
        lds_barrier();
    }

    for (int tp = 0; tp < 8; ++tp) {
        const int t = tp * 2;
        AFREAD(0, 0);
        MFMA3(bqE0);
#pragma unroll
        for (int ni = 0; ni < 3; ++ni)
            bqO0[ni] = *(const s16x8*)(wbq[ni] + (t + 1) * 2048);
        AFREAD(0, 64);
        MFMA3(bqE1);
#pragma unroll
        for (int ni = 0; ni < 3; ++ni)
            bqO1[ni] = *(const s16x8*)(wbq[ni] + (t + 1) * 2048 + 1024);
        *(s16x8*)(smem + 16384 + aw0) = cvt8(pa0, pa1);
        *(s16x8*)(smem + 16384 + aw1) = cvt8(pa2, pa3);
        if (tp < 7) {
            const float* xq = xp + (t + 2) * 64;
            pa0 = *(const f32x4*)(xq);
            pa1 = *(const f32x4*)(xq + 4);
            pa2 = *(const f32x4*)(xq + 8);
            pa3 = *(const f32x4*)(xq + 12);
        }
        lds_barrier();

        AFREAD(16384, 0);
        MFMA3(bqO0);
        if (tp < 7) {
#pragma unroll
            for (int ni = 0; ni < 3; ++ni)
                bqE0[ni] = *(const s16x8*)(wbq[ni] + (t + 2) * 2048);
        }
        AFREAD(16384, 64);
        MFMA3(bqO1);
        if (tp < 7) {
#pragma unroll
            for (int ni = 0; ni < 3; ++ni)
                bqE1[ni] = *(const s16x8*)(wbq[ni] + (t + 2) * 2048 + 1024);
            *(s16x8*)(smem + aw0) = cvt8(pa0, pa1);
            *(s16x8*)(smem + aw1) = cvt8(pa2, pa3);
            const float* xq = xp + (t + 3) * 64;
            pa0 = *(const f32x4*)(xq);
            pa1 = *(const f32x4*)(xq + 4);
            pa2 = *(const f32x4*)(xq + 8);
            pa3 = *(const f32x4*)(xq + 12);
            lds_barrier();
        }
    }

#undef AFREAD
#undef MFMA3

#pragma unroll
    for (int mi = 0; mi < 8; ++mi) {
        int m0 = bm * 128 + mi * 16 + l4 * 4;
#pragma unroll
        for (int ni = 0; ni < 3; ++ni) {
            int nb  = wid * 48 + ni * 16;
            int mat = nb >> 7;
            int col = (nb & 127) + lm;
            if (mat == 2) {
                int bb2 = m0 >> 8, tt = m0 & 255;
                s16x4 w4;
#pragma unroll
                for (int j = 0; j < 4; ++j) w4[j] = (short)f2bf(acc[mi][ni][j]);
                *(s16x4*)(vto + ((size_t)bb2 * 128 + col) * 256 + tt) = w4;
            } else {
                unsigned short* dst = (mat == 0) ? qo : ko;
#pragma unroll
                for (int j = 0; j < 4; ++j)
                    dst[(size_t)(m0 + j) * 128 + col] = f2bf(acc[mi][ni][j]);
            }
        }
    }
}

// ---------------------------------------------------------------------------
// Kernel 2: causal attention (unchanged, verified; ~7µs).
// ---------------------------------------------------------------------------
__global__ __launch_bounds__(512) void attn(
    const unsigned short* __restrict__ q,
    const unsigned short* __restrict__ k,
    const unsigned short* __restrict__ vt,
    float* __restrict__ out) {

    __shared__ char pbuf[65536];

    const int tid = threadIdx.x, wid = tid >> 6, lane = tid & 63;
    const int lm = lane & 15, l4 = lane >> 4;
    const int b = blockIdx.x >> 1, qt = blockIdx.x & 1;
    const int qbase = qt << 7;
    const int t0 = qbase + wid * 16;
    const int nfrags = (qbase + 128) >> 4;
    const int nkf    = (qbase + 128) >> 5;

    const unsigned short* qrow = q + (size_t)(b * 256 + t0 + lm) * 128 + l4 * 8;
    s16x8 qf[4];
#pragma unroll
    for (int kf = 0; kf < 4; ++kf) qf[kf] = *(const s16x8*)(qrow + kf * 32);

    f32x4 sacc[16];
#pragma unroll
    for (int i = 0; i < 16; ++i) sacc[i] = (f32x4)0.f;

    const unsigned short* kbase = k + (size_t)(b * 256) * 128 + l4 * 8;
#pragma unroll
    for (int nf = 0; nf < 16; ++nf) {
        if (nf < nfrags) {
#pragma unroll
            for (int kf = 0; kf < 4; ++kf) {
                s16x8 a = *(const s16x8*)(kbase + (size_t)(nf * 16 + lm) * 128 + kf * 32);
                sacc[nf] = __builtin_amdgcn_mfma_f32_16x16x32_bf16(a, qf[kf], sacc[nf], 0, 0, 0);
            }
        }
    }

    const float scale = 0.08838834764831845f;
    const int tg = t0 + lm;
    float mx = -1e30f;
#pragma unroll
    for (int nf = 0; nf < 16; ++nf) {
        if (nf < nfrags) {
#pragma unroll
            for (int j = 0; j < 4; ++j) {
                int kv = nf * 16 + l4 * 4 + j;
                float s = sacc[nf][j] * scale;
                s = (kv > tg) ? -1e30f : s;
                sacc[nf][j] = s;
                mx = fmaxf(mx, s);
            }
        }
    }
    mx = fmaxf(mx, __shfl_xor(mx, 16));
    mx = fmaxf(mx, __shfl_xor(mx, 32));
    float sum = 0.f;
#pragma unroll
    for (int nf = 0; nf < 16; ++nf) {
        if (nf < nfrags) {
#pragma unroll
            for (int j = 0; j < 4; ++j) {
                float p = __expf(sacc[nf][j] - mx);
                sacc[nf][j] = p;
                sum += p;
            }
        }
    }
    sum += __shfl_xor(sum, 16);
    sum += __shfl_xor(sum, 32);
    float rinv = 1.0f / sum;

    char* pw = pbuf + wid * 8192 + lm * 512;
#pragma unroll
    for (int nf = 0; nf < 16; ++nf) {
        if (nf < nfrags) {
            s16x4 w;
#pragma unroll
            for (int j = 0; j < 4; ++j) w[j] = (short)f2bf(sacc[nf][j] * rinv);
            *(s16x4*)(pw + ((nf * 32 + l4 * 8) ^ ((lm & 7) << 4))) = w;
        }
    }
    asm volatile("s_waitcnt lgkmcnt(0)" ::: "memory");

    f32x4 oacc[8];
#pragma unroll
    for (int i = 0; i < 8; ++i) oacc[i] = (f32x4)0.f;

    const unsigned short* vbase = vt + (size_t)b * 32768 + l4 * 8;
#pragma unroll
    for (int kvf = 0; kvf < 8; ++kvf) {
        if (kvf < nkf) {
            s16x8 pf = *(const s16x8*)(pbuf + wid * 8192 + lm * 512 +
                        ((kvf * 64 + l4 * 16) ^ ((lm & 7) << 4)));
#pragma unroll
            for (int hf = 0; hf < 8; ++hf) {
                s16x8 a = *(const s16x8*)(vbase + (size_t)(hf * 16 + lm) * 256 + kvf * 32);
                oacc[hf] = __builtin_amdgcn_mfma_f32_16x16x32_bf16(a, pf, oacc[hf], 0, 0, 0);
            }
        }
    }

    float* ob = out + (size_t)(b * 256 + t0 + lm) * 128 + l4 * 4;
#pragma unroll
    for (int hf = 0; hf < 8; ++hf)
        *(f32x4*)(ob + hf * 16) = oacc[hf];
}

// ===========================================================================
// DIAGNOSTIC KERNELS (run AFTER attn; write into already-consumed scratch).
// Each loops its phase so its dispatch duration lands in the rocprof top-5
// (cutoff ~74us).  `zero` is runtime-0 (opaque to the compiler) to defeat
// cross-pass load merging.
// ===========================================================================

// diag_x: R11's exact A-load pattern, 8 passes (512KB f32/CU/pass).
__global__ __launch_bounds__(512, 2) void diag_x(
    const float* __restrict__ x, float* __restrict__ outp, int zero) {
    const int tid = threadIdx.x, bm = blockIdx.x;
    const int ar = tid >> 2, acb = (tid & 3) * 16;
    const float* xp = x + (size_t)(bm * 128 + ar) * 1024 + acb;
    f32x4 s0 = (f32x4)0.f, s1 = (f32x4)0.f, s2 = (f32x4)0.f, s3 = (f32x4)0.f;
    for (int pass = 0; pass < 8; ++pass) {
        const float* p = xp + (size_t)pass * zero;
#pragma unroll 4
        for (int t = 0; t < 16; ++t) {
            s0 += *(const f32x4*)(p + t * 64);
            s1 += *(const f32x4*)(p + t * 64 + 4);
            s2 += *(const f32x4*)(p + t * 64 + 8);
            s3 += *(const f32x4*)(p + t * 64 + 12);
        }
    }
    f32x4 s = s0 + s1 + s2 + s3;
    outp[(size_t)bm * 512 + tid] = s[0] + s[1] + s[2] + s[3];
}

// diag_xb: x-loads + B-fragment loads at R11 cadence, no LDS/MFMA, 8 passes.
__global__ __launch_bounds__(512, 2) void diag_xb(
    const float* __restrict__ x, const unsigned char* __restrict__ wt3,
    float* __restrict__ outp, int zero) {
    const int tid = threadIdx.x, bm = blockIdx.x;
    const int lane = tid & 63, wid = tid >> 6;
    const int ar = tid >> 2, acb = (tid & 3) * 16;
    const float* xp = x + (size_t)(bm * 128 + ar) * 1024 + acb;
    const unsigned char* wbq[3];
#pragma unroll
    for (int ni = 0; ni < 3; ++ni)
        wbq[ni] = wt3 + (size_t)(wid * 3 + ni) * 32768 + (size_t)lane * 16;
    f32x4 s0 = (f32x4)0.f, s1 = (f32x4)0.f;
    int h0 = 0, h1 = 0;
    for (int pass = 0; pass < 8; ++pass) {
        const float* p = xp + (size_t)pass * zero;
        const unsigned char* wz = (size_t)pass * zero + (const unsigned char*)0;
#pragma unroll 2
        for (int t = 0; t < 16; ++t) {
            s0 += *(const f32x4*)(p + t * 64);
            s1 += *(const f32x4*)(p + t * 64 + 4);
            s0 += *(const f32x4*)(p + t * 64 + 8);
            s1 += *(const f32x4*)(p + t * 64 + 12);
#pragma unroll
            for (int ni = 0; ni < 3; ++ni) {
                s16x8 v0 = *(const s16x8*)(wbq[ni] + t * 2048 + (size_t)wz);
                s16x8 v1 = *(const s16x8*)(wbq[ni] + t * 2048 + 1024);
                h0 ^= v0[0] ^ v0[7];
                h1 ^= v1[0] ^ v1[7];
            }
        }
    }
    outp[(size_t)bm * 512 + tid] =
        s0[0] + s0[1] + s0[2] + s0[3] + s1[0] + s1[1] + s1[2] + s1[3] +
        (float)(h0 + h1);
}

// diag_mfma: R11's LDS+MFMA+publish+barrier skeleton, no global, 16 passes.
__global__ __launch_bounds__(512, 2) void diag_mfma(
    float* __restrict__ outp, int zero) {
    __shared__ char smem[32768];
    const int tid = threadIdx.x;
    const int lane = tid & 63;
    const int lm = lane & 15, l4 = lane >> 4;
    for (int i = tid; i < 8192; i += 512)
        ((unsigned int*)smem)[i] = (unsigned int)i * 2654435761u;
    __syncthreads();

    f32x4 acc[8][3];
#pragma unroll
    for (int i = 0; i < 8; ++i)
#pragma unroll
        for (int j = 0; j < 3; ++j) acc[i][j] = (f32x4)0.f;
    s16x8 bq[3];
#pragma unroll
    for (int ni = 0; ni < 3; ++ni)
#pragma unroll
        for (int j = 0; j < 8; ++j) bq[ni][j] = (short)(tid * 8 + j + ni);
    int arow[8];
#pragma unroll
    for (int mi = 0; mi < 8; ++mi) arow[mi] = mi * 16 + lm;
    const int ar = tid >> 2, acb = (tid & 3) * 16;
    const int aswz = (ar & 7) << 4;
    const int aw0 = ar * 128 + ((acb * 2) ^ aswz);
    const int aw1 = ar * 128 + ((acb * 2 + 16) ^ aswz);
    s16x8 pub;
#pragma unroll
    for (int j = 0; j < 8; ++j) pub[j] = (short)(tid + j);

    for (int pass = 0; pass < 16; ++pass) {
        for (int t = 0; t < 16; ++t) {
            const int ab = (t & 1) * 16384;
            s16x8 af[8];
#pragma unroll
            for (int kk = 0; kk < 2; ++kk) {
#pragma unroll
                for (int mi = 0; mi < 8; ++mi)
                    af[mi] = *(const s16x8*)(smem + ab + arow[mi] * 128 +
                              ((kk * 64 + l4 * 16) ^ ((arow[mi] & 7) << 4)));
                __builtin_amdgcn_s_setprio(1);
#pragma unroll
                for (int ni = 0; ni < 3; ++ni)
#pragma unroll
                    for (int mi = 0; mi < 8; ++mi)
                        acc[mi][ni] = __builtin_amdgcn_mfma_f32_16x16x32_bf16(
                            af[mi], bq[ni], acc[mi][ni], 0, 0, 0);
                __builtin_amdgcn_s_setprio(0);
            }
            *(s16x8*)(smem + (ab ^ 16384) + aw0 + zero) = pub;
            *(s16x8*)(smem + (ab ^ 16384) + aw1) = pub;
            lds_barrier();
        }
    }
    float s = 0.f;
#pragma unroll
    for (int mi = 0; mi < 8; ++mi)
#pragma unroll
        for (int ni = 0; ni < 3; ++ni)
            s += acc[mi][ni][0] + acc[mi][ni][1] + acc[mi][ni][2] + acc[mi][ni][3];
    outp[(size_t)blockIdx.x * 512 + tid] = s;
}

// ---------------------------------------------------------------------------
extern "C" void kernel_launch(void* const* d_in, const int* in_sizes, int n_in,
                              void* d_out, int out_size, void* d_ws, size_t ws_size,
                              hipStream_t stream) {
    const float* x  = (const float*)d_in[0];
    const float* Wq = (const float*)d_in[1];
    const float* Wk = (const float*)d_in[2];
    const float* Wv = (const float*)d_in[3];
    float* out = (float*)d_out;

    char* ws = (char*)d_ws;
    unsigned char*  wt = (unsigned char*)(ws);                     // fragment-major
    unsigned short* qb = (unsigned short*)(ws + 786432);
    unsigned short* kb = (unsigned short*)(ws + 786432 + 8388608);
    unsigned short* vb = (unsigned short*)(ws + 786432 + 2 * 8388608);

    const int zero = in_sizes[0] - 33554432;   // runtime 0, opaque to compiler

    prep_wt<<<384, 256, 0, stream>>>(Wq, Wk, Wv, wt);
    qkv_gemm<<<256, 512, 0, stream>>>(x, wt, qb, kb, vb);
    attn<<<256, 512, 0, stream>>>(qb, kb, vb, out);

    // diagnostics — write into regions already consumed by attn
    diag_x   <<<256, 512, 0, stream>>>(x, (float*)qb, zero);
    diag_xb  <<<256, 512, 0, stream>>>(x, wt, (float*)kb, zero);
    diag_mfma<<<256, 512, 0, stream>>>((float*)vb, zero);
}